// Round 17
// baseline (44.103 us; speedup 1.0000x reference)
//
#include <hip/hip_runtime.h>

// ConvDistanceTransform closed form:
//   D = Chebyshev distance transform of seeds (exact, separable)
//   i = (D-1)/3 ; out = 3.5*i - 0.35*log( sum_{q in 7x7, D(q)<=3i} exp(-|p-q|_2/0.35) )
// R17 = R16 minus y-split: full-column 32-col blocks (stage s1 ONCE), 262-row
// colpass, epilogue thread = 4 cols x 8 rows with 14 shared window rows and
// early FIN retirement. Integer math identical to R16 (absmax 0.375).

typedef unsigned short u16x4 __attribute__((ext_vector_type(4)));

#define BIGV (1 << 20)
#define ROWB 272  // u8 d1 row: 8 guard + 256 + 8 guard
#define CHB (256 * ROWB)

// ---------- Kernel A: per-row 1-D distance, wave-per-row register scans ----------
__global__ __launch_bounds__(256) void k_rowdist(const float* __restrict__ img,
                                                 unsigned char* __restrict__ d1) {
  const int lane = threadIdx.x & 63;
  const int wv = threadIdx.x >> 6;
  const int nwg = (int)gridDim.x;
  const int o = (int)blockIdx.x;
  const int l = (o & 7) * (nwg >> 3) + (o >> 3);  // XCD-chunk swizzle
  const int row = l * 4 + wv;  // ch*256 + y
  const int x0 = lane * 4;

  const float4 v = *reinterpret_cast<const float4*>(&img[(size_t)row * 256 + x0]);

  int c0 = (v.x != 0.0f) ? -x0 : BIGV;
  int c1 = (v.y != 0.0f) ? -(x0 + 1) : BIGV;
  int c2 = (v.z != 0.0f) ? -(x0 + 2) : BIGV;
  int c3 = (v.w != 0.0f) ? -(x0 + 3) : BIGV;
  const int p0 = c0;
  const int p1 = min(c1, p0);
  const int p2 = min(c2, p1);
  const int p3 = min(c3, p2);
  int incl = p3;
#pragma unroll
  for (int off = 1; off < 64; off <<= 1) {
    int o2 = __shfl_up(incl, off, 64);
    if (lane >= off) incl = min(incl, o2);
  }
  int excl = __shfl_up(incl, 1, 64);
  if (lane == 0) excl = BIGV;
  const int df0 = x0 + min(p0, excl);
  const int df1 = x0 + 1 + min(p1, excl);
  const int df2 = x0 + 2 + min(p2, excl);
  const int df3 = x0 + 3 + min(p3, excl);

  int g0 = (v.x != 0.0f) ? x0 : BIGV;
  int g1 = (v.y != 0.0f) ? (x0 + 1) : BIGV;
  int g2 = (v.z != 0.0f) ? (x0 + 2) : BIGV;
  int g3 = (v.w != 0.0f) ? (x0 + 3) : BIGV;
  const int q3 = g3;
  const int q2 = min(g2, q3);
  const int q1 = min(g1, q2);
  const int q0 = min(g0, q1);
  int incl2 = q0;
#pragma unroll
  for (int off = 1; off < 64; off <<= 1) {
    int o2 = __shfl_down(incl2, off, 64);
    if (lane < 64 - off) incl2 = min(incl2, o2);
  }
  int excl2 = __shfl_down(incl2, 1, 64);
  if (lane == 63) excl2 = BIGV;
  const int db0 = min(q0, excl2) - x0;
  const int db1 = min(q1, excl2) - (x0 + 1);
  const int db2 = min(q2, excl2) - (x0 + 2);
  const int db3 = min(q3, excl2) - (x0 + 3);

  const unsigned int d0 = (unsigned int)min(min(df0, db0), 127);
  const unsigned int d1v = (unsigned int)min(min(df1, db1), 127);
  const unsigned int d2 = (unsigned int)min(min(df2, db2), 127);
  const unsigned int d3 = (unsigned int)min(min(df3, db3), 127);
  const int ch = row >> 8, y = row & 255;
  const size_t base = (size_t)ch * CHB + (size_t)y * ROWB;
  *reinterpret_cast<unsigned int*>(&d1[base + 8 + x0]) =
      d0 | (d1v << 8) | (d2 << 16) | (d3 << 24);
  if (lane < 2)
    *reinterpret_cast<unsigned int*>(&d1[base + lane * 4]) = 0u;
  else if (lane >= 62)
    *reinterpret_cast<unsigned int*>(&d1[base + 264 + (lane - 62) * 4]) = 0u;
}

#define LDQ(off) (*reinterpret_cast<const u16x4*>(&s1[(off)]))
#define EMIN __builtin_elementwise_min
#define EMAX __builtin_elementwise_max

// ---- epilogue: row-major shared-align tap scatter ----
#define IND(q_, CP) ((((q_) + (CP)) & 0x80808080u) >> 7)

#define PT0(s_)                                                                 \
  aD##s_ += IND(q0, Cp##s_); aD##s_ += IND(q1, Cp##s_);                         \
  aC##s_ += IND(q2, Cp##s_); aC##s_ += IND(q3, Cp##s_);                         \
  aC##s_ += IND(q4, Cp##s_); aD##s_ += IND(q5, Cp##s_);                         \
  aD##s_ += IND(q6, Cp##s_);
#define PT1(s_)                                                                 \
  aD##s_ += IND(q0, Cp##s_); aC##s_ += IND(q1, Cp##s_);                         \
  aB##s_ += IND(q2, Cp##s_); aB##s_ += IND(q3, Cp##s_);                         \
  aB##s_ += IND(q4, Cp##s_); aC##s_ += IND(q5, Cp##s_);                         \
  aD##s_ += IND(q6, Cp##s_);
#define PT2(s_)                                                                 \
  aC##s_ += IND(q0, Cp##s_); aB##s_ += IND(q1, Cp##s_);                         \
  aA##s_ += IND(q2, Cp##s_); aA##s_ += IND(q3, Cp##s_);                         \
  aA##s_ += IND(q4, Cp##s_); aB##s_ += IND(q5, Cp##s_);                         \
  aC##s_ += IND(q6, Cp##s_);
#define PT3(s_) /* center row: dx=0 skipped */                                  \
  aC##s_ += IND(q0, Cp##s_); aB##s_ += IND(q1, Cp##s_);                         \
  aA##s_ += IND(q2, Cp##s_);                                                    \
  aA##s_ += IND(q4, Cp##s_); aB##s_ += IND(q5, Cp##s_);                         \
  aC##s_ += IND(q6, Cp##s_);

#define ROWU(u_, ...)                                                           \
  do {                                                                          \
    const unsigned char* pu_ = &Ds[(rl0 + (u_)) * 44 + jb2];                    \
    const unsigned int R0_ = *reinterpret_cast<const unsigned int*>(pu_);       \
    const unsigned int R1_ = *reinterpret_cast<const unsigned int*>(pu_ + 4);   \
    const unsigned int R2_ = *reinterpret_cast<const unsigned int*>(pu_ + 8);   \
    const unsigned int q0 = __builtin_amdgcn_alignbyte(R1_, R0_, 1);            \
    const unsigned int q1 = __builtin_amdgcn_alignbyte(R1_, R0_, 2);            \
    const unsigned int q2 = __builtin_amdgcn_alignbyte(R1_, R0_, 3);            \
    const unsigned int q3 = R1_;                                                \
    const unsigned int q4 = __builtin_amdgcn_alignbyte(R2_, R1_, 1);            \
    const unsigned int q5 = __builtin_amdgcn_alignbyte(R2_, R1_, 2);            \
    const unsigned int q6 = __builtin_amdgcn_alignbyte(R2_, R1_, 3);            \
    (void)q0; (void)q1; (void)q2; (void)q3; (void)q4; (void)q5; (void)q6;       \
    __VA_ARGS__                                                                 \
  } while (0)

#define CPSET(s_, DC)                                                           \
  const unsigned int Cp##s_ =                                                   \
      (unsigned int)(127 - 3 * ((max((int)((DC)&255u) - 1, 0) * 86) >> 8)) |    \
      ((unsigned int)(127 - 3 * ((max((int)(((DC) >> 8) & 255u) - 1, 0) * 86) >> 8)) << 8) | \
      ((unsigned int)(127 - 3 * ((max((int)(((DC) >> 16) & 255u) - 1, 0) * 86) >> 8)) << 16) | \
      ((unsigned int)(127 - 3 * ((max((int)((DC) >> 24) - 1, 0) * 86) >> 8)) << 24)

#define FIN(s_, DC)                                                             \
  do {                                                                          \
    const int d0_ = (int)((DC)&255u);                                           \
    const int d1_ = (int)(((DC) >> 8) & 255u);                                  \
    const int d2_ = (int)(((DC) >> 16) & 255u);                                 \
    const int d3_ = (int)((DC) >> 24);                                          \
    const int i0_ = (max(d0_ - 1, 0) * 86) >> 8;                                \
    const int i1_ = (max(d1_ - 1, 0) * 86) >> 8;                                \
    const int i2_ = (max(d2_ - 1, 0) * 86) >> 8;                                \
    const int i3_ = (max(d3_ - 1, 0) * 86) >> 8;                                \
    const float s0_ = fmaf((float)(aA##s_ & 255u), wA,                          \
                     fmaf((float)(aB##s_ & 255u), wB,                           \
                     fmaf((float)(aC##s_ & 255u), wC,                           \
                          (float)(aD##s_ & 255u) * wD)));                       \
    const float s1_ = fmaf((float)((aA##s_ >> 8) & 255u), wA,                   \
                     fmaf((float)((aB##s_ >> 8) & 255u), wB,                    \
                     fmaf((float)((aC##s_ >> 8) & 255u), wC,                    \
                          (float)((aD##s_ >> 8) & 255u) * wD)));                \
    const float s2_ = fmaf((float)((aA##s_ >> 16) & 255u), wA,                  \
                     fmaf((float)((aB##s_ >> 16) & 255u), wB,                   \
                     fmaf((float)((aC##s_ >> 16) & 255u), wC,                   \
                          (float)((aD##s_ >> 16) & 255u) * wD)));               \
    const float s3_ = fmaf((float)(aA##s_ >> 24), wA,                           \
                     fmaf((float)(aB##s_ >> 24), wB,                            \
                     fmaf((float)(aC##s_ >> 24), wC,                            \
                          (float)(aD##s_ >> 24) * wD)));                        \
    const float cv0_ = W4 - s0_, cv1_ = W4 - s1_;                               \
    const float cv2_ = W4 - s2_, cv3_ = W4 - s3_;                               \
    const float e0_ = fmaf(3.5f, (float)i0_, -0.35f * __logf(fmaxf(cv0_, 1e-30f))); \
    const float e1_ = fmaf(3.5f, (float)i1_, -0.35f * __logf(fmaxf(cv1_, 1e-30f))); \
    const float e2_ = fmaf(3.5f, (float)i2_, -0.35f * __logf(fmaxf(cv2_, 1e-30f))); \
    const float e3_ = fmaf(3.5f, (float)i3_, -0.35f * __logf(fmaxf(cv3_, 1e-30f))); \
    const float4 o4_ = make_float4(                                             \
        (d0_ > 0 && cv0_ > 1e-6f) ? e0_ : 0.0f,                                 \
        (d1_ > 0 && cv1_ > 1e-6f) ? e1_ : 0.0f,                                 \
        (d2_ > 0 && cv2_ > 1e-6f) ? e2_ : 0.0f,                                 \
        (d3_ > 0 && cv3_ > 1e-6f) ? e3_ : 0.0f);                                \
    *reinterpret_cast<float4*>(&out[obase + (size_t)(s_) * 256]) = o4_;         \
  } while (0)

// ---------- Kernel B: full-column 32-col blocks; colpass + 8-row epilogue ----------
__global__ __launch_bounds__(256) void k_fused(const unsigned char* __restrict__ d1,
                                               float* __restrict__ out) {
  const int nwg = (int)gridDim.x;  // nch*8
  const int o = (int)blockIdx.x;
  const int l = (o & 7) * (nwg >> 3) + (o >> 3);  // XCD-chunk swizzle
  const int xt = l & 7;
  const int ch = l >> 3;
  const int x0 = xt * 32;
  const int tid = threadIdx.x;
  const int lastxt = 7;

  __shared__ __align__(16) unsigned char s1[256 * 96];  // u16; col j <-> img x0-8+j
  __shared__ __align__(16) unsigned char Ds[262 * 44];  // u8; row r <-> y = r-3

  // ---- stage u8 d1 (48 cols, 256 rows) ONCE, expand to u16 via perm ----
  const unsigned char* src = d1 + (size_t)ch * CHB + x0;
#pragma unroll
  for (int it = 0; it < 3; ++it) {
    const int idx = it * 256 + tid;     // 0..767
    const int y = (idx * 21846) >> 16;  // /3
    const int seg = idx - y * 3;
    const uint4 q = *reinterpret_cast<const uint4*>(&src[y * ROWB + seg * 16]);
    uint4 lo, hi;
    lo.x = __builtin_amdgcn_perm(0u, q.x, 0x0C010C00u);
    lo.y = __builtin_amdgcn_perm(0u, q.x, 0x0C030C02u);
    lo.z = __builtin_amdgcn_perm(0u, q.y, 0x0C010C00u);
    lo.w = __builtin_amdgcn_perm(0u, q.y, 0x0C030C02u);
    hi.x = __builtin_amdgcn_perm(0u, q.z, 0x0C010C00u);
    hi.y = __builtin_amdgcn_perm(0u, q.z, 0x0C030C02u);
    hi.z = __builtin_amdgcn_perm(0u, q.w, 0x0C010C00u);
    hi.w = __builtin_amdgcn_perm(0u, q.w, 0x0C030C02u);
    *reinterpret_cast<uint4*>(&s1[y * 96 + seg * 32]) = lo;
    *reinterpret_cast<uint4*>(&s1[y * 96 + seg * 32 + 16]) = hi;
  }
  __syncthreads();

  // ---- column pass: 262 rows (y=-3..258) x 10 quads = 2620 tasks ----
  const u16x4 K1 = {1, 1, 1, 1}, K2 = {2, 2, 2, 2}, K3 = {3, 3, 3, 3},
              K4 = {4, 4, 4, 4}, K5 = {5, 5, 5, 5}, K6 = {6, 6, 6, 6},
              K7 = {7, 7, 7, 7}, K8 = {8, 8, 8, 8};
#pragma unroll 1
  for (int it = 0; it < 11; ++it) {
    const int idx = it * 256 + tid;  // 0..2815
    if (idx >= 2620) break;
    const int r = (idx * 6554) >> 16;  // /10 (exact for idx<5000)
    const int g = idx - r * 10;
    const int y = r - 3;
    const bool ghost =
        (xt == 0 && g == 0) || (xt == lastxt && g == 9) || y < 0 || y > 255;
    if (ghost) {
      *reinterpret_cast<unsigned int*>(&Ds[r * 44 + g * 4]) = 0x7F7F7F7Fu;
      continue;
    }
    const int jb = 8 + 8 * g;
    const int rb = y * 96 + jb;
    const int bot = 255 * 96 + jb;
    const u16x4 b0 = LDQ(rb);
    const u16x4 u1 = LDQ(max(rb - 96, jb));
    const u16x4 u2 = LDQ(max(rb - 192, jb));
    const u16x4 u3 = LDQ(max(rb - 288, jb));
    const u16x4 u4 = LDQ(max(rb - 384, jb));
    const u16x4 u5 = LDQ(max(rb - 480, jb));
    const u16x4 u6 = LDQ(max(rb - 576, jb));
    const u16x4 u7 = LDQ(max(rb - 672, jb));
    const u16x4 u8 = LDQ(max(rb - 768, jb));
    const u16x4 w1 = LDQ(min(rb + 96, bot));
    const u16x4 w2 = LDQ(min(rb + 192, bot));
    const u16x4 w3 = LDQ(min(rb + 288, bot));
    const u16x4 w4 = LDQ(min(rb + 384, bot));
    const u16x4 w5 = LDQ(min(rb + 480, bot));
    const u16x4 w6 = LDQ(min(rb + 576, bot));
    const u16x4 w7 = LDQ(min(rb + 672, bot));
    const u16x4 w8 = LDQ(min(rb + 768, bot));
    const u16x4 mu = EMIN(EMIN(EMIN(EMAX(u1, K1), EMAX(u2, K2)),
                                EMIN(EMAX(u3, K3), EMAX(u4, K4))),
                          EMIN(EMIN(EMAX(u5, K5), EMAX(u6, K6)),
                                EMIN(EMAX(u7, K7), EMAX(u8, K8))));
    const u16x4 mw = EMIN(EMIN(EMIN(EMAX(w1, K1), EMAX(w2, K2)),
                                EMIN(EMAX(w3, K3), EMAX(w4, K4))),
                          EMIN(EMIN(EMAX(w5, K5), EMAX(w6, K6)),
                                EMIN(EMAX(w7, K7), EMAX(w8, K8))));
    u16x4 b = EMIN(b0, EMIN(mu, mw));
    unsigned long long bb = __builtin_bit_cast(unsigned long long, b);
    unsigned int blo = (unsigned int)bb, bhi = (unsigned int)(bb >> 32);
    int bm = max(max((int)(blo & 0xFFFFu), (int)(blo >> 16)),
                 max((int)(bhi & 0xFFFFu), (int)(bhi >> 16)));
    int k = 9;
    int au = rb - 768, ad = rb + 768;
    while (k < bm) {  // over-iterations are provable no-ops
      const unsigned short t1 = (unsigned short)k, t2 = (unsigned short)(k + 1),
                           t3 = (unsigned short)(k + 2), t4 = (unsigned short)(k + 3);
      const u16x4 c1 = {t1, t1, t1, t1}, c2 = {t2, t2, t2, t2},
                  c3 = {t3, t3, t3, t3}, c4 = {t4, t4, t4, t4};
      const u16x4 a1 = LDQ(max(au - 96, jb));
      const u16x4 a2 = LDQ(max(au - 192, jb));
      const u16x4 a3 = LDQ(max(au - 288, jb));
      const u16x4 a4 = LDQ(max(au - 384, jb));
      const u16x4 e1 = LDQ(min(ad + 96, bot));
      const u16x4 e2 = LDQ(min(ad + 192, bot));
      const u16x4 e3 = LDQ(min(ad + 288, bot));
      const u16x4 e4 = LDQ(min(ad + 384, bot));
      const u16x4 t = EMIN(EMIN(EMIN(EMAX(a1, c1), EMAX(a2, c2)),
                                 EMIN(EMAX(a3, c3), EMAX(a4, c4))),
                           EMIN(EMIN(EMAX(e1, c1), EMAX(e2, c2)),
                                 EMIN(EMAX(e3, c3), EMAX(e4, c4))));
      b = EMIN(b, t);
      au -= 384;
      ad += 384;
      k += 4;
      bb = __builtin_bit_cast(unsigned long long, b);
      blo = (unsigned int)bb;
      bhi = (unsigned int)(bb >> 32);
      bm = max(max((int)(blo & 0xFFFFu), (int)(blo >> 16)),
               max((int)(bhi & 0xFFFFu), (int)(bhi >> 16)));
    }
    const unsigned int packed = __builtin_amdgcn_perm(bhi, blo, 0x06040200u);
    *reinterpret_cast<unsigned int*>(&Ds[r * 44 + g * 4]) = packed;
  }
  __syncthreads();

  // ---- epilogue: thread = 4 cols x 8 rows; 14 shared window rows ----
  const float wA = 3.17814e-2f, wB = 2.35426e-3f, wC = 1.91126e-4f, wD = 1.35150e-5f;
  const float W4 = 8.0f * wA + 12.0f * wB + 16.0f * wC + 12.0f * wD;

  const int cg = tid & 7;   // col group: center cols x0+4cg .. +3
  const int rg = tid >> 3;  // 0..31 (8 rows each)
  const int rl0 = rg * 8;   // Ds row base (output y = rl0 + s)
  const int jb2 = cg * 4;
  const size_t obase = (size_t)ch * 65536 + (size_t)rl0 * 256 + x0 + cg * 4;

  const unsigned int Dc0 =
      *reinterpret_cast<const unsigned int*>(&Ds[(rl0 + 3) * 44 + jb2 + 4]);
  const unsigned int Dc1 =
      *reinterpret_cast<const unsigned int*>(&Ds[(rl0 + 4) * 44 + jb2 + 4]);
  const unsigned int Dc2 =
      *reinterpret_cast<const unsigned int*>(&Ds[(rl0 + 5) * 44 + jb2 + 4]);
  const unsigned int Dc3 =
      *reinterpret_cast<const unsigned int*>(&Ds[(rl0 + 6) * 44 + jb2 + 4]);
  const unsigned int Dc4 =
      *reinterpret_cast<const unsigned int*>(&Ds[(rl0 + 7) * 44 + jb2 + 4]);
  const unsigned int Dc5 =
      *reinterpret_cast<const unsigned int*>(&Ds[(rl0 + 8) * 44 + jb2 + 4]);
  const unsigned int Dc6 =
      *reinterpret_cast<const unsigned int*>(&Ds[(rl0 + 9) * 44 + jb2 + 4]);
  const unsigned int Dc7 =
      *reinterpret_cast<const unsigned int*>(&Ds[(rl0 + 10) * 44 + jb2 + 4]);
  CPSET(0, Dc0); CPSET(1, Dc1); CPSET(2, Dc2); CPSET(3, Dc3);
  CPSET(4, Dc4); CPSET(5, Dc5); CPSET(6, Dc6); CPSET(7, Dc7);

  unsigned int aA0 = 0, aB0 = 0, aC0 = 0, aD0 = 0;
  unsigned int aA1 = 0, aB1 = 0, aC1 = 0, aD1 = 0;
  unsigned int aA2 = 0, aB2 = 0, aC2 = 0, aD2 = 0;
  unsigned int aA3 = 0, aB3 = 0, aC3 = 0, aD3 = 0;
  unsigned int aA4 = 0, aB4 = 0, aC4 = 0, aD4 = 0;
  unsigned int aA5 = 0, aB5 = 0, aC5 = 0, aD5 = 0;
  unsigned int aA6 = 0, aB6 = 0, aC6 = 0, aD6 = 0;
  unsigned int aA7 = 0, aB7 = 0, aC7 = 0, aD7 = 0;

  ROWU(0, PT0(0));
  ROWU(1, PT1(0) PT0(1));
  ROWU(2, PT2(0) PT1(1) PT0(2));
  ROWU(3, PT3(0) PT2(1) PT1(2) PT0(3));
  ROWU(4, PT2(0) PT3(1) PT2(2) PT1(3) PT0(4));
  ROWU(5, PT1(0) PT2(1) PT3(2) PT2(3) PT1(4) PT0(5));
  ROWU(6, PT0(0) PT1(1) PT2(2) PT3(3) PT2(4) PT1(5) PT0(6));
  FIN(0, Dc0);
  ROWU(7, PT0(1) PT1(2) PT2(3) PT3(4) PT2(5) PT1(6) PT0(7));
  FIN(1, Dc1);
  ROWU(8, PT0(2) PT1(3) PT2(4) PT3(5) PT2(6) PT1(7));
  FIN(2, Dc2);
  ROWU(9, PT0(3) PT1(4) PT2(5) PT3(6) PT2(7));
  FIN(3, Dc3);
  ROWU(10, PT0(4) PT1(5) PT2(6) PT3(7));
  FIN(4, Dc4);
  ROWU(11, PT0(5) PT1(6) PT2(7));
  FIN(5, Dc5);
  ROWU(12, PT0(6) PT1(7));
  FIN(6, Dc6);
  ROWU(13, PT0(7));
  FIN(7, Dc7);
}

extern "C" void kernel_launch(void* const* d_in, const int* in_sizes, int n_in,
                              void* d_out, int out_size, void* d_ws, size_t ws_size,
                              hipStream_t stream) {
  const float* img = (const float*)d_in[0];
  float* out = (float*)d_out;
  unsigned char* Dbuf = (unsigned char*)d_ws;

  const int total = in_sizes[0];  // B*C*H*W
  const int nch = total >> 16;    // B*C (H=W=256)

  k_rowdist<<<dim3(nch * 64), dim3(256), 0, stream>>>(img, Dbuf);
  k_fused<<<dim3(nch * 8), dim3(256), 0, stream>>>(Dbuf, out);
}